// Round 1
// baseline (428.419 us; speedup 1.0000x reference)
//
#include <hip/hip_runtime.h>
#include <hip/hip_bf16.h>
#include <stdint.h>

// Problem constants
#define NIMG   32
#define CCH    256
#define WDIM   56
#define HW     3136          // 56*56
#define MTOT   (NIMG*HW)     // 100352 = 784 * 128
#define KCTOT  36            // 4 ci-chunks * 9 taps
#define BK     64

typedef __attribute__((ext_vector_type(8))) short    bf16x8;
typedef __attribute__((ext_vector_type(4))) float    f32x4;
typedef __attribute__((ext_vector_type(4))) uint32_t u32x4;

typedef __attribute__((address_space(1))) const uint8_t* as1cp;
typedef __attribute__((address_space(3))) uint8_t*       as3p;

// ---------------- prepass: dequantize weights -> bf16, layout [co][kc][cil] ----------------
// Bw[(co*36 + cc*9 + tap)*64 + cil] = bf16( lut[ widx[co][cc*64+cil][tap] ] )
__global__ __launch_bounds__(256) void dequant_weights(
    const int* __restrict__ widx, const float* __restrict__ lut,
    uint16_t* __restrict__ Bw) {
  int idx = blockIdx.x * 256 + threadIdx.x;        // < 256*36*64 = 589824
  int co  = idx / (KCTOT * BK);
  int r   = idx - co * (KCTOT * BK);
  int kc  = r >> 6;
  int cil = r & 63;
  int cc  = kc / 9;
  int tap = kc - cc * 9;
  int ci  = cc * 64 + cil;
  int wv  = widx[(co * CCH + ci) * 9 + tap];
  uint32_t b  = __float_as_uint(lut[wv]);
  uint32_t rn = (b + 0x7fffu + ((b >> 16) & 1u)) >> 16;   // RN-even to bf16
  Bw[idx] = (uint16_t)rn;
}

// ---------------- main: implicit-GEMM conv via MFMA ----------------
// C[m][co] = sum_{tap,ci} A(m; ci,tap) * W[co][ci][tap],  A = shifted/masked input (bf16)
__global__ __launch_bounds__(256) void conv_mfma(
    const float* __restrict__ in, const uint16_t* __restrict__ Bw,
    const float* __restrict__ bias, float* __restrict__ out) {

  // A: 128 rows (m) x 64 k, row stride 72 elems (144 B) -> conflict-free frag reads
  __shared__ __align__(16) uint16_t A_lds[128 * 72];
  // B: 128 rows (co) x 64 k, row stride 64 elems (128 B), XOR-swizzled 16B granules
  __shared__ __align__(16) uint16_t B_lds[128 * 64];

  const int t    = threadIdx.x;
  const int lane = t & 63;
  const int wv   = t >> 6;          // wave 0..3
  const int wm   = wv & 1;          // wave m-tile (0..1)
  const int wn   = wv >> 1;         // wave n-tile (0..1)
  const int lrow = lane & 15;
  const int kgrp = lane >> 4;       // 0..3

  const int m0  = blockIdx.x * 128;
  const int co0 = blockIdx.y * 128;

  // ---- per-thread A-staging geometry (one m-row per thread) ----
  const int m_loc   = t & 127;
  const int cg_base = t >> 7;                   // 0 or 1
  const int m_idx   = m0 + m_loc;
  const int n_img   = m_idx / HW;
  const int s       = m_idx - n_img * HW;
  const int h       = s / WDIM;
  const int w       = s - h * WDIM;
  const float* in_base = in + (size_t)n_img * (CCH * HW) + s;

  f32x4 acc[4][4];
#pragma unroll
  for (int i = 0; i < 4; ++i)
#pragma unroll
    for (int j = 0; j < 4; ++j)
      acc[i][j] = (f32x4){0.f, 0.f, 0.f, 0.f};

  // B staging lane constants
  const int b_seg_row = lane >> 3;  // 0..7 row within 8-row segment
  const int b_g       = lane & 7;   // stored granule

#pragma unroll 1
  for (int cc = 0; cc < 4; ++cc) {
#pragma unroll 1
    for (int tap = 0; tap < 9; ++tap) {
      const int kh = tap / 3;
      const int dh = kh - 1;
      const int dw = (tap - kh * 3) - 1;
      const int kc = cc * 9 + tap;

      // ---- stage B: global_load_lds, 16 B/lane, lane-linear LDS dest ----
      // layout: element (co_l, kchunk ck) stored at byte co_l*128 + (ck ^ (co_l&7))*16
#pragma unroll
      for (int c = 0; c < 4; ++c) {
        const int co_l = wv * 32 + c * 8 + b_seg_row;
        const int ck   = b_g ^ (co_l & 7);     // which global 16B chunk this lane fetches
        const uint8_t* gsrc =
            (const uint8_t*)(Bw + ((size_t)(co0 + co_l) * KCTOT + kc) * BK) + ck * 16;
        uint8_t* ldst = (uint8_t*)B_lds + (wv * 32 + c * 8) * 128;  // wave-uniform base
        __builtin_amdgcn_global_load_lds((as1cp)gsrc, (as3p)ldst, 16, 0, 0);
      }

      // ---- stage A: fp32 gather -> bf16 truncate-pack -> ds_write_b128 ----
      const bool valid = ((unsigned)(h + dh) < 56u) & ((unsigned)(w + dw) < 56u);
      const long off0  = (long)cc * (64 * HW) + dh * WDIM + dw;
#pragma unroll
      for (int i = 0; i < 4; ++i) {
        const int cg = cg_base + 2 * i;        // 8-ci group 0..7
        u32x4 pk;
        if (valid) {
          const float* p = in_base + off0 + (long)cg * (8 * HW);
#pragma unroll
          for (int jj = 0; jj < 4; ++jj) {
            uint32_t b0 = __float_as_uint(p[(2 * jj) * HW]);
            uint32_t b1 = __float_as_uint(p[(2 * jj + 1) * HW]);
            pk[jj] = (b0 >> 16) | (b1 & 0xffff0000u);
          }
        } else {
          pk = (u32x4){0u, 0u, 0u, 0u};        // zero-padding rows/cols
        }
        *(u32x4*)((uint8_t*)A_lds + m_loc * 144 + cg * 16) = pk;
      }

      __syncthreads();   // drains vmcnt (global_load_lds) + lgkmcnt (ds_write)

      // ---- MFMA: 2 k-steps x 4x4 subtiles ----
#pragma unroll
      for (int ks = 0; ks < 2; ++ks) {
        bf16x8 af[4], bfb[4];
#pragma unroll
        for (int mi = 0; mi < 4; ++mi) {
          const int row = wm * 64 + mi * 16 + lrow;
          af[mi] = *(const bf16x8*)((const uint8_t*)A_lds + row * 144 + ks * 64 + kgrp * 16);
        }
#pragma unroll
        for (int ni = 0; ni < 4; ++ni) {
          const int nrow = wn * 64 + ni * 16 + lrow;
          const int gran = (ks * 4 + kgrp) ^ (nrow & 7);   // undo XOR swizzle
          bfb[ni] = *(const bf16x8*)((const uint8_t*)B_lds + nrow * 128 + gran * 16);
        }
#pragma unroll
        for (int mi = 0; mi < 4; ++mi)
#pragma unroll
          for (int ni = 0; ni < 4; ++ni)
            acc[mi][ni] = __builtin_amdgcn_mfma_f32_16x16x32_bf16(
                af[mi], bfb[ni], acc[mi][ni], 0, 0, 0);
      }

      __syncthreads();   // protect LDS before next chunk overwrites
    }
  }

  // ---- epilogue: add bias, store (D: row=(lane>>4)*4+r, col=lane&15) ----
  float bv[4];
#pragma unroll
  for (int ni = 0; ni < 4; ++ni)
    bv[ni] = bias[co0 + wn * 64 + ni * 16 + lrow];

#pragma unroll
  for (int mi = 0; mi < 4; ++mi) {
#pragma unroll
    for (int r = 0; r < 4; ++r) {
      const int mrow = m0 + wm * 64 + mi * 16 + kgrp * 4 + r;
      const int ni_img = mrow / HW;
      const int ss = mrow - ni_img * HW;
      float* ob = out + (size_t)ni_img * (CCH * HW) + ss;
#pragma unroll
      for (int ni = 0; ni < 4; ++ni) {
        const int co = co0 + wn * 64 + ni * 16 + lrow;
        ob[(size_t)co * HW] = acc[mi][ni][r] + bv[ni];
      }
    }
  }
}

extern "C" void kernel_launch(void* const* d_in, const int* in_sizes, int n_in,
                              void* d_out, int out_size, void* d_ws, size_t ws_size,
                              hipStream_t stream) {
  const float* in   = (const float*)d_in[0];
  const int*   widx = (const int*)d_in[1];
  const float* lut  = (const float*)d_in[2];
  const float* bias = (const float*)d_in[3];
  float* out = (float*)d_out;
  uint16_t* Bw = (uint16_t*)d_ws;   // 589824 * 2 B = 1.18 MB scratch

  dequant_weights<<<dim3(589824 / 256), dim3(256), 0, stream>>>(widx, lut, Bw);
  conv_mfma<<<dim3(MTOT / 128, CCH / 128), dim3(256), 0, stream>>>(in, Bw, bias, out);
}